// Round 6
// baseline (338.326 us; speedup 1.0000x reference)
//
#include <hip/hip_runtime.h>
#include <hip/hip_bf16.h>
#include <math.h>

// DownConvFace: 3 stages of {mesh_conv -> BN(global stats) -> (+res) -> LeakyReLU(0.2)}
// B=4, F=50000, Cin=32/64/64, O=64, fp32 in/out.
//
// R12: kill the conv epilogue LDS round trip. Under R11's wave->channel mapping,
// acc[nt] already holds (4 channels x face nt*16+l15), so:
//  - BN stats accumulate IN REGISTERS (S4/Q4 f32x4 per lane over owned faces);
//    kernel-end 16-lane shfl_xor butterfly; channels are wave-exclusive -> no
//    cross-wave reduce; lane l15==0 writes pS/pQ[blk][c..c+3].
//  - Y stored DIRECTLY from acc: uint2 (2x cvt_pk) per nt; a wave covers 16
//    faces x contiguous 32B, 4 waves tile the 128B row -> L2 merges full lines.
//  - fp32 tile region + barriers B3/B4 deleted: 2 barriers/tile (B1 G-ready,
//    B2 G-consumed). LDS = G only: CIN=32 16KB (8 blocks/CU, grid 2048),
//    CIN=64 32KB (5 blocks/CU, grid 1280; conv2 no longer 3-capped).
// KEEP: persistent blocks, reg-staged gather pipeline, weights in VGPRs,
// kernel-boundary stats sync (R9: NO fence/atomics in persistent kernels),
// norm_res fusion, inline-norm gather in conv2, cvt_pk packing.

typedef __attribute__((ext_vector_type(8))) short short8;
typedef __attribute__((ext_vector_type(8))) unsigned short ushort8_t;
typedef __attribute__((ext_vector_type(4))) float f32x4;

__device__ inline unsigned short f2bf(float v) {
    union { float f; unsigned u; } x; x.f = v;
    unsigned r = x.u + 0x7fffu + ((x.u >> 16) & 1u);   // RNE
    return (unsigned short)(r >> 16);
}
__device__ inline float bf2f(unsigned short u) {
    union { unsigned u; float f; } x; x.u = ((unsigned)u) << 16; return x.f;
}
// packed RNE f32x2 -> bf16x2 (v_cvt_pk_bf16_f32); lo 16 bits = a, hi = b
__device__ inline unsigned pk2(float a, float b) {
    union { __hip_bfloat162 h; unsigned u; } c;
    c.h = __float22bfloat162_rn(make_float2(a, b));
    return c.u;
}

// fe [B][32][F] fp32 -> fe_t [B][F][32] bf16; first 160 blocks also cast weights.
// grid (ceil(F/64), B), block 256.
__global__ void transpose_fe_kernel(const float* __restrict__ fe,
                                    unsigned short* __restrict__ o, int F,
                                    const float* __restrict__ w1,
                                    const float* __restrict__ w2a,
                                    const float* __restrict__ w2b,
                                    unsigned short* __restrict__ w1b,
                                    unsigned short* __restrict__ w2ab,
                                    unsigned short* __restrict__ w2bb)
{
    __shared__ float tile[64 * 33];
    const int b = blockIdx.y;
    const int f0 = blockIdx.x * 64;
    const int t = threadIdx.x;

    {   // folded weight cast (w1: 8192 elems; w2a/w2b: 16384 each)
        const int bid = blockIdx.y * gridDim.x + blockIdx.x;
        if (bid < 32)       { const int i = bid * 256 + t;        w1b[i]  = f2bf(w1[i]);  }
        else if (bid < 96)  { const int i = (bid - 32) * 256 + t; w2ab[i] = f2bf(w2a[i]); }
        else if (bid < 160) { const int i = (bid - 96) * 256 + t; w2bb[i] = f2bf(w2b[i]); }
    }

    const int lane = t & 63;
    const int w = t >> 6;
    const int f = f0 + lane;
    if (f < F) {
#pragma unroll
        for (int i = 0; i < 8; ++i) {
            const int c = w * 8 + i;
            tile[lane * 33 + c] = fe[((size_t)b * 32 + c) * F + f];
        }
    }
    __syncthreads();
    const int j = t >> 2, s = t & 3;
    const int fj = f0 + j;
    if (fj < F) {
        unsigned fw[4];
#pragma unroll
        for (int i = 0; i < 4; ++i)
            fw[i] = pk2(tile[j * 33 + s * 8 + 2 * i], tile[j * 33 + s * 8 + 2 * i + 1]);
        *(uint4*)(o + ((size_t)b * F + fj) * 32 + s * 8) = make_uint4(fw[0], fw[1], fw[2], fw[3]);
    }
}

// Persistent fused mesh-conv GEMM + BN block-stats. Block 256 (4 waves), 64
// faces/tile. Wave wv owns channels [wv*16,wv*16+16); weights in VGPRs; LDS = G
// only; stats in registers; Y stored direct from acc. 2 barriers/tile.
template <int CIN, bool NORM>
__launch_bounds__(256, (CIN == 32) ? 8 : 5)
__global__ void conv_mfma_kernel(const unsigned short* __restrict__ x,  // [B][F][CIN] bf16
                                 const int*   __restrict__ gidx,        // [B][F][3]
                                 const unsigned short* __restrict__ wb, // [64][K] bf16
                                 const float* __restrict__ bias,        // [64]
                                 const float* __restrict__ mrIn,        // [2][64] or null
                                 unsigned short* __restrict__ y,        // [B*F][64] bf16
                                 float* __restrict__ pS,                // [NBg][64]
                                 float* __restrict__ pQ,                // [NBg][64]
                                 int nb, int nbx, int F)
{
    constexpr int NSEG = CIN / 32;
    constexpr int K    = 4 * CIN;
    constexpr int RB   = 2 * K;                        // row bytes (pow2)
    constexpr int GB   = 64 * RB;                      // G bytes (16384 / 32768)
    __shared__ __align__(16) unsigned char smem[GB];

    const int NBg = gridDim.x;
    const int t = threadIdx.x;
    const int j = t >> 2, s = t & 3;                   // 4 threads per face/row
    const int lane = t & 63, wv = t >> 6;
    const int l15 = lane & 15, quad = lane >> 4;
    const int kb = quad * 8;

    unsigned char* grow = smem + j * RB;
    const int swz = (j & 7) << 4;

    // ---- weights -> REGISTERS: row wv*16+l15, 16B col slice per (ksi,quad) ----
    short8 afr[K / 32];
    {
        const int ar = wv * 16 + l15;
#pragma unroll
        for (int ksi = 0; ksi < K / 32; ++ksi)
            afr[ksi] = *(const short8*)(wb + (size_t)ar * K + ksi * 32 + kb);
    }
    // ---- bias -> registers (channels wv*16+quad*4 .. +3) ----
    const f32x4 bias4 = *(const f32x4*)(bias + wv * 16 + quad * 4);

    // ---- NORM affine (per-channel, uniform over tiles) -> registers ----
    float scr[NSEG * 8], shr[NSEG * 8];
    if constexpr (NORM) {
#pragma unroll
        for (int i = 0; i < NSEG; ++i) {
            const int c0 = (i * 4 + s) * 8;
#pragma unroll
            for (int h = 0; h < 2; ++h) {
                const f32x4 a  = *(const f32x4*)(mrIn + c0 + 4 * h);
                const f32x4 sh = *(const f32x4*)(mrIn + 64 + c0 + 4 * h);
#pragma unroll
                for (int q = 0; q < 4; ++q) {
                    scr[i * 8 + 4 * h + q] = a[q];
                    shr[i * 8 + 4 * h + q] = sh[q];
                }
            }
        }
    }

    // ---- staging registers + register stats ----
    ushort8_t vc[NSEG], v0[NSEG], v1[NSEG], v2[NSEG];
    int gA0, gA1, gA2;                                 // gidx for tile tl+NBg
    f32x4 S4 = {0.f, 0.f, 0.f, 0.f}, Q4 = {0.f, 0.f, 0.f, 0.f};

    int tl = blockIdx.x;                               // grid <= nb guaranteed

    // prologue: gather tile tl (clamped rows; invalid faces masked at epilogue)
    {
        const int b0 = tl / nbx;
        const int f0 = (tl - b0 * nbx) * 64;
        const int fc = min(f0 + j, F - 1);
        const int* gp = gidx + ((size_t)b0 * F + fc) * 3;
        const int g0 = gp[0], g1 = gp[1], g2 = gp[2];
        const unsigned short* xb = x + (size_t)b0 * F * CIN;
        const unsigned short* pc = xb + (size_t)fc * CIN;
        const unsigned short* p0 = xb + (size_t)g0 * CIN;
        const unsigned short* p1 = xb + (size_t)g1 * CIN;
        const unsigned short* p2 = xb + (size_t)g2 * CIN;
#pragma unroll
        for (int i = 0; i < NSEG; ++i) {
            const int c0 = (i * 4 + s) * 8;
            vc[i] = *(const ushort8_t*)(pc + c0);
            v0[i] = *(const ushort8_t*)(p0 + c0);
            v1[i] = *(const ushort8_t*)(p1 + c0);
            v2[i] = *(const ushort8_t*)(p2 + c0);
        }
    }
    {   // prefetch gidx one tile ahead
        const int tn = min(tl + NBg, nb - 1);
        const int bn = tn / nbx;
        const int fn = min((tn - bn * nbx) * 64 + j, F - 1);
        const int* gp = gidx + ((size_t)bn * F + fn) * 3;
        gA0 = gp[0]; gA1 = gp[1]; gA2 = gp[2];
    }

    for (; tl < nb; tl += NBg) {
        const int b  = tl / nbx;
        const int f0 = (tl - b * nbx) * 64;

        // ---- feat(cur regs) -> LDS G (inline norm if NORM; cvt_pk packing) ----
#pragma unroll
        for (int i = 0; i < NSEG; ++i) {
            const int c0 = (i * 4 + s) * 8;
            unsigned fw[16];
#pragma unroll
            for (int q = 0; q < 8; ++q) {
                float ctr = bf2f(vc[i][q]);
                float a   = bf2f(v0[i][q]);
                float bb  = bf2f(v1[i][q]);
                float cc  = bf2f(v2[i][q]);
                if constexpr (NORM) {
                    const float sc_ = scr[i * 8 + q], sh_ = shr[i * 8 + q];
                    ctr = fmaf(ctr, sc_, sh_); ctr = fmaxf(ctr, 0.2f * ctr);
                    a   = fmaf(a,   sc_, sh_); a   = fmaxf(a,   0.2f * a);
                    bb  = fmaf(bb,  sc_, sh_); bb  = fmaxf(bb,  0.2f * bb);
                    cc  = fmaf(cc,  sc_, sh_); cc  = fmaxf(cc,  0.2f * cc);
                }
                const float su = a + bb + cc;
                const float dd = fabsf(a - bb) + fabsf(bb - cc) + fabsf(cc - a);
                const float mm = fmaxf(a, fmaxf(bb, cc));
                fw[2 * q]     = pk2(ctr, su);
                fw[2 * q + 1] = pk2(dd, mm);
            }
#pragma unroll
            for (int q4 = 0; q4 < 4; ++q4) {
                const int qb = 8 * c0 + 16 * q4;       // 16B chunk byte offset
                *(uint4*)(grow + (qb ^ swz)) =
                    make_uint4(fw[4 * q4], fw[4 * q4 + 1], fw[4 * q4 + 2], fw[4 * q4 + 3]);
            }
        }

        // ---- issue gathers for tile tl+NBg; they fly over MFMA+epilogue ----
        {
            const int tn = min(tl + NBg, nb - 1);
            const int bn = tn / nbx;
            const int fcn = min((tn - bn * nbx) * 64 + j, F - 1);
            const unsigned short* xb = x + (size_t)bn * F * CIN;
            const unsigned short* pc = xb + (size_t)fcn * CIN;
            const unsigned short* p0 = xb + (size_t)gA0 * CIN;
            const unsigned short* p1 = xb + (size_t)gA1 * CIN;
            const unsigned short* p2 = xb + (size_t)gA2 * CIN;
#pragma unroll
            for (int i = 0; i < NSEG; ++i) {
                const int c0 = (i * 4 + s) * 8;
                vc[i] = *(const ushort8_t*)(pc + c0);
                v0[i] = *(const ushort8_t*)(p0 + c0);
                v1[i] = *(const ushort8_t*)(p1 + c0);
                v2[i] = *(const ushort8_t*)(p2 + c0);
            }
            const int t2 = min(tl + 2 * NBg, nb - 1);
            const int b2 = t2 / nbx;
            const int f2 = min((t2 - b2 * nbx) * 64 + j, F - 1);
            const int* gp = gidx + ((size_t)b2 * F + f2) * 3;
            gA0 = gp[0]; gA1 = gp[1]; gA2 = gp[2];
        }
        __syncthreads();                               // B1: G ready

        // ---- MFMA: weights from VGPRs, G rows (faces nt*16+l15) from LDS ----
        f32x4 acc[4];
#pragma unroll
        for (int nt = 0; nt < 4; ++nt) acc[nt] = (f32x4){0.f, 0.f, 0.f, 0.f};
#pragma unroll
        for (int ksi = 0; ksi < K / 32; ++ksi) {
            const int cb = 2 * (ksi * 32 + kb);
#pragma unroll
            for (int nt = 0; nt < 4; ++nt) {
                const int nr = nt * 16 + l15;
                const short8 bfr = *(const short8*)(smem + nr * RB + (cb ^ ((nr & 7) << 4)));
                acc[nt] = __builtin_amdgcn_mfma_f32_16x16x32_bf16(afr[ksi], bfr, acc[nt], 0, 0, 0);
            }
        }
        __syncthreads();                               // B2: G consumed -> next feat ok

        // ---- epilogue: register-only. bias + stats accum + direct Y store ----
#pragma unroll
        for (int nt = 0; nt < 4; ++nt) {
            const f32x4 av = acc[nt] + bias4;
            const int f = f0 + nt * 16 + l15;
            if (f < F) {
                S4 += av;
                Q4 += av * av;
                unsigned short* yp = y + ((size_t)b * F + f) * 64 + wv * 16 + quad * 4;
                *(uint2*)yp = make_uint2(pk2(av[0], av[1]), pk2(av[2], av[3]));
            }
        }
    }

    // ---- tail: 16-lane butterfly (channels are wave-exclusive), one store ----
#pragma unroll
    for (int m = 1; m <= 8; m <<= 1) {
#pragma unroll
        for (int q = 0; q < 4; ++q) {
            S4[q] += __shfl_xor(S4[q], m);
            Q4[q] += __shfl_xor(Q4[q], m);
        }
    }
    if (l15 == 0) {
        const int c0 = wv * 16 + quad * 4;
        *(f32x4*)(pS + (size_t)blockIdx.x * 64 + c0) = S4;
        *(f32x4*)(pQ + (size_t)blockIdx.x * 64 + c0) = Q4;
    }
}

// grid 64 (one block per channel), 256 threads. Reads [NBg][64] partials.
__global__ void finalize_kernel(const float* __restrict__ pS, const float* __restrict__ pQ,
                                int nbg, float invN,
                                const float* __restrict__ gamma,
                                const float* __restrict__ beta,
                                float* __restrict__ mr)
{
    __shared__ float rs_[256], rq_[256];
    const int o = blockIdx.x, t = threadIdx.x;
    float S = 0.f, Q = 0.f;
    for (int jj = t; jj < nbg; jj += 256) {
        S += pS[(size_t)jj * 64 + o];
        Q += pQ[(size_t)jj * 64 + o];
    }
    rs_[t] = S; rq_[t] = Q;
    __syncthreads();
#pragma unroll
    for (int s = 128; s > 0; s >>= 1) {
        if (t < s) { rs_[t] += rs_[t + s]; rq_[t] += rq_[t + s]; }
        __syncthreads();
    }
    if (t == 0) {
        const float mu  = rs_[0] * invN;
        const float var = rq_[0] * invN - mu * mu;
        const float rsg = rsqrtf(var + 1e-5f);
        const float sc  = gamma[o] * rsg;
        mr[o]      = sc;
        mr[64 + o] = fmaf(-sc, mu, beta[o]);
    }
}

// x2 = lrelu(aff2(Y2) + lrelu(aff1(Y1))): reads Y1,Y2 bf16 -> writes x2 bf16.
__global__ void norm_res_kernel(const unsigned short* __restrict__ y1,  // [M][64]
                                const unsigned short* __restrict__ y2,  // [M][64]
                                const float* __restrict__ mr1,
                                const float* __restrict__ mr2,
                                unsigned short* __restrict__ out,       // [M][64]
                                int N8)
{
    const int tid = blockIdx.x * blockDim.x + threadIdx.x;
    if (tid >= N8) return;
    const int c0 = (tid & 7) * 8;
    const ushort8_t a = *(const ushort8_t*)(y1 + (size_t)tid * 8);
    const ushort8_t b = *(const ushort8_t*)(y2 + (size_t)tid * 8);
    float r[8];
#pragma unroll
    for (int h = 0; h < 2; ++h) {
        const f32x4 s1 = *(const f32x4*)(mr1 + c0 + 4 * h);
        const f32x4 h1 = *(const f32x4*)(mr1 + 64 + c0 + 4 * h);
        const f32x4 s2 = *(const f32x4*)(mr2 + c0 + 4 * h);
        const f32x4 h2 = *(const f32x4*)(mr2 + 64 + c0 + 4 * h);
#pragma unroll
        for (int i = 0; i < 4; ++i) {
            float x1 = fmaf(bf2f(a[4 * h + i]), s1[i], h1[i]);
            x1 = fmaxf(x1, 0.2f * x1);
            float v = fmaf(bf2f(b[4 * h + i]), s2[i], h2[i]) + x1;
            r[4 * h + i] = fmaxf(v, 0.2f * v);
        }
    }
    unsigned fw[4];
#pragma unroll
    for (int i = 0; i < 4; ++i) fw[i] = pk2(r[2 * i], r[2 * i + 1]);
    *(uint4*)(out + (size_t)tid * 8) = make_uint4(fw[0], fw[1], fw[2], fw[3]);
}

// Final BN+res+lrelu fused with transpose [B*F][64] -> [B][64][F] fp32 (d_out).
__global__ void norm_transpose_kernel(const unsigned short* __restrict__ y,   // bf16
                                      const unsigned short* __restrict__ res, // bf16
                                      const float* __restrict__ mr,
                                      float* __restrict__ out, int F)
{
    __shared__ float tile[64 * 65];
    const int b = blockIdx.y, f0 = blockIdx.x * 64, t = threadIdx.x;
    const int j = t >> 2, s = t & 3;
    const int f = f0 + j;
    if (f < F) {
        const size_t row = ((size_t)b * F + f) * 64;
#pragma unroll
        for (int i = 0; i < 2; ++i) {
            const int c0 = s * 16 + i * 8;
            const ushort8_t yv = *(const ushort8_t*)(y + row + c0);
            const ushort8_t rv = *(const ushort8_t*)(res + row + c0);
#pragma unroll
            for (int h = 0; h < 2; ++h) {
                const f32x4 sc = *(const f32x4*)(mr + c0 + 4 * h);
                const f32x4 sh = *(const f32x4*)(mr + 64 + c0 + 4 * h);
#pragma unroll
                for (int q = 0; q < 4; ++q) {
                    float vv = fmaf(bf2f(yv[4 * h + q]), sc[q], sh[q]) + bf2f(rv[4 * h + q]);
                    vv = fmaxf(vv, 0.2f * vv);
                    tile[(c0 + 4 * h + q) * 65 + j] = vv;
                }
            }
        }
    }
    __syncthreads();
    const int o = t >> 2;
    float* ob = out + ((size_t)b * 64 + o) * F + f0;
#pragma unroll
    for (int i = 0; i < 4; ++i) {
        const int fs = (i * 4 + s) * 4;
        if (f0 + fs < F) {
            f32x4 v;
#pragma unroll
            for (int q = 0; q < 4; ++q) v[q] = tile[o * 65 + fs + q];
            *(f32x4*)(ob + fs) = v;
        }
    }
}

extern "C" void kernel_launch(void* const* d_in, const int* in_sizes, int n_in,
                              void* d_out, int out_size, void* d_ws, size_t ws_size,
                              hipStream_t stream)
{
    const float* fe  = (const float*)d_in[0];
    const int*   gm  = (const int*)d_in[1];
    const float* w1  = (const float*)d_in[2];
    const float* b1  = (const float*)d_in[3];
    const float* w2a = (const float*)d_in[4];
    const float* b2a = (const float*)d_in[5];
    const float* w2b = (const float*)d_in[6];
    const float* b2b = (const float*)d_in[7];
    const float* g0  = (const float*)d_in[8];
    const float* be0 = (const float*)d_in[9];
    const float* g1  = (const float*)d_in[10];
    const float* be1 = (const float*)d_in[11];
    const float* g2  = (const float*)d_in[12];
    const float* be2 = (const float*)d_in[13];

    const int B = 4, O = 64;
    const int F = in_sizes[0] / (B * 32);
    const int M = B * F;
    const float invN = 1.0f / (float)M;
    const int nbx = (F + 63) / 64;
    const int nb  = nbx * B;

    // Workspace layout
    unsigned short* Y1 = (unsigned short*)d_ws;         // [M][64] bf16 (Y1, later Y3)
    unsigned short* Y2 = Y1 + (size_t)M * O;            // [M][64] bf16
    unsigned short* x2 = Y2 + (size_t)M * O;            // [M][64] bf16
    float* pS  = (float*)(x2 + (size_t)M * O);          // [<=2048][64]
    float* pQ  = pS + 2048 * 64;                        // [<=2048][64]
    float* mr1 = pQ + 2048 * 64;                        // [2][64]
    float* mr2 = mr1 + 128;
    float* mr3 = mr2 + 128;
    unsigned short* w1b  = (unsigned short*)(mr3 + 128);// [64][128]
    unsigned short* w2ab = w1b + 64 * 128;              // [64][256]
    unsigned short* w2bb = w2ab + 64 * 256;             // [64][256]
    unsigned short* fe_t = (unsigned short*)d_out;      // [B][F][32] bf16, dead after conv1

    dim3 blk(256);
    dim3 tgrid(nbx, B);
    const int N8 = M * 8;
    dim3 ngrid((N8 + 255) / 256);
    const int g1g = (nb < 2048) ? nb : 2048;            // conv1: 8 blocks/CU
    const int g2g = (nb < 1280) ? nb : 1280;            // conv2/3: 5 blocks/CU
    const int g3g = g2g;

    transpose_fe_kernel<<<tgrid, blk, 0, stream>>>(fe, fe_t, F,
                                                   w1, w2a, w2b, w1b, w2ab, w2bb);

    // Stage 1: conv1 -> Y1, block stats -> pS/pQ; finalize -> mr1
    conv_mfma_kernel<32, false><<<g1g, blk, 0, stream>>>(
        fe_t, gm, w1b, b1, nullptr, Y1, pS, pQ, nb, nbx, F);
    finalize_kernel<<<64, 256, 0, stream>>>(pS, pQ, g1g, invN, g0, be0, mr1);

    // Stage 2: conv2 gathers Y1 with inline norm1 -> Y2; finalize -> mr2
    conv_mfma_kernel<64, true><<<g2g, blk, 0, stream>>>(
        Y1, gm, w2ab, b2a, mr1, Y2, pS, pQ, nb, nbx, F);
    finalize_kernel<<<64, 256, 0, stream>>>(pS, pQ, g2g, invN, g1, be1, mr2);

    // x2 = lrelu(aff2(Y2) + lrelu(aff1(Y1)))
    norm_res_kernel<<<ngrid, blk, 0, stream>>>(Y1, Y2, mr1, mr2, x2, N8);

    // Stage 3: conv3 gathers x2 -> Y3 (reuses Y1 slot); finalize -> mr3
    conv_mfma_kernel<64, false><<<g3g, blk, 0, stream>>>(
        x2, gm, w2bb, b2b, nullptr, Y1, pS, pQ, nb, nbx, F);
    finalize_kernel<<<64, 256, 0, stream>>>(pS, pQ, g3g, invN, g2, be2, mr3);

    // out = lrelu(aff3(Y3) + x2), transposed to [B][64][F] fp32
    norm_transpose_kernel<<<tgrid, blk, 0, stream>>>(Y1, x2, mr3, (float*)d_out, F);
}

// Round 7
// 251.258 us; speedup vs baseline: 1.3465x; 1.3465x over previous
//
#include <hip/hip_runtime.h>
#include <hip/hip_bf16.h>
#include <math.h>

// DownConvFace: 3 stages of {mesh_conv -> BN(global stats) -> (+res) -> LeakyReLU(0.2)}
// B=4, F=50000, Cin=32/64/64, O=64, fp32 in/out.
//
// R13: revert R12's direct Y store (8B/lane partial-line scatter -> 5x HBM
// amplification: FETCH 144MB, WRITE 150MB, RMW on every sector). Back to R11's
// LDS-tile coalesced store (proven ~27MB WRITE), KEEPING R12's register BN stats
// (S4/Q4 from av in the epilogue; stats LDS pass deleted; 16-lane butterfly tail
// — channels are wave-exclusive under the wave->channel mapping).
// Structure per tile: feat||gather-issue -> B1 -> MFMA -> B2 -> av->LDS tile
// -> B3 -> coalesced Y store -> B4. LDS = max(G, fp32 tile) (17408 / 32768).
// KEEP: persistent blocks, reg-staged gather pipeline, weights in VGPRs,
// kernel-boundary stats sync (R9: NO fence/atomics in persistent kernels),
// norm_res fusion, inline-norm gather in conv2, cvt_pk packing.

typedef __attribute__((ext_vector_type(8))) short short8;
typedef __attribute__((ext_vector_type(8))) unsigned short ushort8_t;
typedef __attribute__((ext_vector_type(4))) float f32x4;

__device__ inline unsigned short f2bf(float v) {
    union { float f; unsigned u; } x; x.f = v;
    unsigned r = x.u + 0x7fffu + ((x.u >> 16) & 1u);   // RNE
    return (unsigned short)(r >> 16);
}
__device__ inline float bf2f(unsigned short u) {
    union { unsigned u; float f; } x; x.u = ((unsigned)u) << 16; return x.f;
}
// packed RNE f32x2 -> bf16x2 (v_cvt_pk_bf16_f32); lo 16 bits = a, hi = b
__device__ inline unsigned pk2(float a, float b) {
    union { __hip_bfloat162 h; unsigned u; } c;
    c.h = __float22bfloat162_rn(make_float2(a, b));
    return c.u;
}

// fe [B][32][F] fp32 -> fe_t [B][F][32] bf16; first 160 blocks also cast weights.
// grid (ceil(F/64), B), block 256.
__global__ void transpose_fe_kernel(const float* __restrict__ fe,
                                    unsigned short* __restrict__ o, int F,
                                    const float* __restrict__ w1,
                                    const float* __restrict__ w2a,
                                    const float* __restrict__ w2b,
                                    unsigned short* __restrict__ w1b,
                                    unsigned short* __restrict__ w2ab,
                                    unsigned short* __restrict__ w2bb)
{
    __shared__ float tile[64 * 33];
    const int b = blockIdx.y;
    const int f0 = blockIdx.x * 64;
    const int t = threadIdx.x;

    {   // folded weight cast (w1: 8192 elems; w2a/w2b: 16384 each)
        const int bid = blockIdx.y * gridDim.x + blockIdx.x;
        if (bid < 32)       { const int i = bid * 256 + t;        w1b[i]  = f2bf(w1[i]);  }
        else if (bid < 96)  { const int i = (bid - 32) * 256 + t; w2ab[i] = f2bf(w2a[i]); }
        else if (bid < 160) { const int i = (bid - 96) * 256 + t; w2bb[i] = f2bf(w2b[i]); }
    }

    const int lane = t & 63;
    const int w = t >> 6;
    const int f = f0 + lane;
    if (f < F) {
#pragma unroll
        for (int i = 0; i < 8; ++i) {
            const int c = w * 8 + i;
            tile[lane * 33 + c] = fe[((size_t)b * 32 + c) * F + f];
        }
    }
    __syncthreads();
    const int j = t >> 2, s = t & 3;
    const int fj = f0 + j;
    if (fj < F) {
        unsigned fw[4];
#pragma unroll
        for (int i = 0; i < 4; ++i)
            fw[i] = pk2(tile[j * 33 + s * 8 + 2 * i], tile[j * 33 + s * 8 + 2 * i + 1]);
        *(uint4*)(o + ((size_t)b * F + fj) * 32 + s * 8) = make_uint4(fw[0], fw[1], fw[2], fw[3]);
    }
}

// Persistent fused mesh-conv GEMM + BN block-stats. Block 256 (4 waves), 64
// faces/tile. Wave wv owns channels [wv*16,wv*16+16); weights in VGPRs; BN stats
// in registers; Y staged through LDS fp32 tile for full-line coalesced stores.
template <int CIN, bool NORM>
__launch_bounds__(256, (CIN == 32) ? 5 : 4)
__global__ void conv_mfma_kernel(const unsigned short* __restrict__ x,  // [B][F][CIN] bf16
                                 const int*   __restrict__ gidx,        // [B][F][3]
                                 const unsigned short* __restrict__ wb, // [64][K] bf16
                                 const float* __restrict__ bias,        // [64]
                                 const float* __restrict__ mrIn,        // [2][64] or null
                                 unsigned short* __restrict__ y,        // [B*F][64] bf16
                                 float* __restrict__ pS,                // [NBg][64]
                                 float* __restrict__ pQ,                // [NBg][64]
                                 int nb, int nbx, int F)
{
    constexpr int NSEG = CIN / 32;
    constexpr int K    = 4 * CIN;
    constexpr int RB   = 2 * K;                        // row bytes (pow2)
    constexpr int GB   = 64 * RB;                      // G bytes (16384 / 32768)
    constexpr int GREG = (GB > 17408) ? GB : 17408;    // G region also holds fp32 tile
    __shared__ __align__(16) unsigned char smem[GREG];
    float* tile = (float*)smem;                        // [64][68] fp32 (reuses G)

    const int NBg = gridDim.x;
    const int t = threadIdx.x;
    const int j = t >> 2, s = t & 3;                   // 4 threads per face/row
    const int lane = t & 63, wv = t >> 6;
    const int l15 = lane & 15, quad = lane >> 4;
    const int kb = quad * 8;

    unsigned char* grow = smem + j * RB;
    const int swz = (j & 7) << 4;

    // ---- weights -> REGISTERS: row wv*16+l15, 16B col slice per (ksi,quad) ----
    short8 afr[K / 32];
    {
        const int ar = wv * 16 + l15;
#pragma unroll
        for (int ksi = 0; ksi < K / 32; ++ksi)
            afr[ksi] = *(const short8*)(wb + (size_t)ar * K + ksi * 32 + kb);
    }
    // ---- bias -> registers (channels wv*16+quad*4 .. +3) ----
    const f32x4 bias4 = *(const f32x4*)(bias + wv * 16 + quad * 4);

    // ---- NORM affine (per-channel, uniform over tiles) -> registers ----
    float scr[NSEG * 8], shr[NSEG * 8];
    if constexpr (NORM) {
#pragma unroll
        for (int i = 0; i < NSEG; ++i) {
            const int c0 = (i * 4 + s) * 8;
#pragma unroll
            for (int h = 0; h < 2; ++h) {
                const f32x4 a  = *(const f32x4*)(mrIn + c0 + 4 * h);
                const f32x4 sh = *(const f32x4*)(mrIn + 64 + c0 + 4 * h);
#pragma unroll
                for (int q = 0; q < 4; ++q) {
                    scr[i * 8 + 4 * h + q] = a[q];
                    shr[i * 8 + 4 * h + q] = sh[q];
                }
            }
        }
    }

    // ---- staging registers + register stats ----
    ushort8_t vc[NSEG], v0[NSEG], v1[NSEG], v2[NSEG];
    int gA0, gA1, gA2;                                 // gidx for tile tl+NBg
    f32x4 S4 = {0.f, 0.f, 0.f, 0.f}, Q4 = {0.f, 0.f, 0.f, 0.f};

    int tl = blockIdx.x;                               // grid <= nb guaranteed

    // prologue: gather tile tl (clamped rows; invalid faces masked at epilogue)
    {
        const int b0 = tl / nbx;
        const int f0 = (tl - b0 * nbx) * 64;
        const int fc = min(f0 + j, F - 1);
        const int* gp = gidx + ((size_t)b0 * F + fc) * 3;
        const int g0 = gp[0], g1 = gp[1], g2 = gp[2];
        const unsigned short* xb = x + (size_t)b0 * F * CIN;
        const unsigned short* pc = xb + (size_t)fc * CIN;
        const unsigned short* p0 = xb + (size_t)g0 * CIN;
        const unsigned short* p1 = xb + (size_t)g1 * CIN;
        const unsigned short* p2 = xb + (size_t)g2 * CIN;
#pragma unroll
        for (int i = 0; i < NSEG; ++i) {
            const int c0 = (i * 4 + s) * 8;
            vc[i] = *(const ushort8_t*)(pc + c0);
            v0[i] = *(const ushort8_t*)(p0 + c0);
            v1[i] = *(const ushort8_t*)(p1 + c0);
            v2[i] = *(const ushort8_t*)(p2 + c0);
        }
    }
    {   // prefetch gidx one tile ahead
        const int tn = min(tl + NBg, nb - 1);
        const int bn = tn / nbx;
        const int fn = min((tn - bn * nbx) * 64 + j, F - 1);
        const int* gp = gidx + ((size_t)bn * F + fn) * 3;
        gA0 = gp[0]; gA1 = gp[1]; gA2 = gp[2];
    }

    for (; tl < nb; tl += NBg) {
        const int b  = tl / nbx;
        const int f0 = (tl - b * nbx) * 64;

        // ---- feat(cur regs) -> LDS G (inline norm if NORM; cvt_pk packing) ----
#pragma unroll
        for (int i = 0; i < NSEG; ++i) {
            const int c0 = (i * 4 + s) * 8;
            unsigned fw[16];
#pragma unroll
            for (int q = 0; q < 8; ++q) {
                float ctr = bf2f(vc[i][q]);
                float a   = bf2f(v0[i][q]);
                float bb  = bf2f(v1[i][q]);
                float cc  = bf2f(v2[i][q]);
                if constexpr (NORM) {
                    const float sc_ = scr[i * 8 + q], sh_ = shr[i * 8 + q];
                    ctr = fmaf(ctr, sc_, sh_); ctr = fmaxf(ctr, 0.2f * ctr);
                    a   = fmaf(a,   sc_, sh_); a   = fmaxf(a,   0.2f * a);
                    bb  = fmaf(bb,  sc_, sh_); bb  = fmaxf(bb,  0.2f * bb);
                    cc  = fmaf(cc,  sc_, sh_); cc  = fmaxf(cc,  0.2f * cc);
                }
                const float su = a + bb + cc;
                const float dd = fabsf(a - bb) + fabsf(bb - cc) + fabsf(cc - a);
                const float mm = fmaxf(a, fmaxf(bb, cc));
                fw[2 * q]     = pk2(ctr, su);
                fw[2 * q + 1] = pk2(dd, mm);
            }
#pragma unroll
            for (int q4 = 0; q4 < 4; ++q4) {
                const int qb = 8 * c0 + 16 * q4;       // 16B chunk byte offset
                *(uint4*)(grow + (qb ^ swz)) =
                    make_uint4(fw[4 * q4], fw[4 * q4 + 1], fw[4 * q4 + 2], fw[4 * q4 + 3]);
            }
        }

        // ---- issue gathers for tile tl+NBg; they fly over MFMA+epilogue ----
        {
            const int tn = min(tl + NBg, nb - 1);
            const int bn = tn / nbx;
            const int fcn = min((tn - bn * nbx) * 64 + j, F - 1);
            const unsigned short* xb = x + (size_t)bn * F * CIN;
            const unsigned short* pc = xb + (size_t)fcn * CIN;
            const unsigned short* p0 = xb + (size_t)gA0 * CIN;
            const unsigned short* p1 = xb + (size_t)gA1 * CIN;
            const unsigned short* p2 = xb + (size_t)gA2 * CIN;
#pragma unroll
            for (int i = 0; i < NSEG; ++i) {
                const int c0 = (i * 4 + s) * 8;
                vc[i] = *(const ushort8_t*)(pc + c0);
                v0[i] = *(const ushort8_t*)(p0 + c0);
                v1[i] = *(const ushort8_t*)(p1 + c0);
                v2[i] = *(const ushort8_t*)(p2 + c0);
            }
            const int t2 = min(tl + 2 * NBg, nb - 1);
            const int b2 = t2 / nbx;
            const int f2 = min((t2 - b2 * nbx) * 64 + j, F - 1);
            const int* gp = gidx + ((size_t)b2 * F + f2) * 3;
            gA0 = gp[0]; gA1 = gp[1]; gA2 = gp[2];
        }
        __syncthreads();                               // B1: G ready

        // ---- MFMA: weights from VGPRs, G rows (faces nt*16+l15) from LDS ----
        f32x4 acc[4];
#pragma unroll
        for (int nt = 0; nt < 4; ++nt) acc[nt] = (f32x4){0.f, 0.f, 0.f, 0.f};
#pragma unroll
        for (int ksi = 0; ksi < K / 32; ++ksi) {
            const int cb = 2 * (ksi * 32 + kb);
#pragma unroll
            for (int nt = 0; nt < 4; ++nt) {
                const int nr = nt * 16 + l15;
                const short8 bfr = *(const short8*)(smem + nr * RB + (cb ^ ((nr & 7) << 4)));
                acc[nt] = __builtin_amdgcn_mfma_f32_16x16x32_bf16(afr[ksi], bfr, acc[nt], 0, 0, 0);
            }
        }
        __syncthreads();                               // B2: G consumed -> reuse as tile

        // ---- epilogue: av = acc+bias; REGISTER stats; av -> LDS tile ----
        {
            const int cb0 = wv * 16 + quad * 4;
#pragma unroll
            for (int nt = 0; nt < 4; ++nt) {
                const f32x4 av = acc[nt] + bias4;
                const int face = nt * 16 + l15;
                if (f0 + face < F) { S4 += av; Q4 += av * av; }
                *(f32x4*)(tile + face * 68 + cb0) = av;
            }
        }
        __syncthreads();                               // B3: tile ready
        {   // coalesced bf16 Y store: thread (j,s) stores 32B of face j's row
            const int f = f0 + j;
            if (f < F) {
                unsigned fw[8];
#pragma unroll
                for (int ii = 0; ii < 8; ++ii)
                    fw[ii] = pk2(tile[j * 68 + s * 16 + 2 * ii],
                                 tile[j * 68 + s * 16 + 2 * ii + 1]);
                unsigned short* yp = y + ((size_t)b * F + f) * 64 + s * 16;
                *(uint4*)yp       = make_uint4(fw[0], fw[1], fw[2], fw[3]);
                *(uint4*)(yp + 8) = make_uint4(fw[4], fw[5], fw[6], fw[7]);
            }
        }
        __syncthreads();                               // B4: tile dead before next feat
    }

    // ---- tail: 16-lane butterfly (channels are wave-exclusive), one store ----
#pragma unroll
    for (int m = 1; m <= 8; m <<= 1) {
#pragma unroll
        for (int q = 0; q < 4; ++q) {
            S4[q] += __shfl_xor(S4[q], m);
            Q4[q] += __shfl_xor(Q4[q], m);
        }
    }
    if (l15 == 0) {
        const int c0 = wv * 16 + quad * 4;
        *(f32x4*)(pS + (size_t)blockIdx.x * 64 + c0) = S4;
        *(f32x4*)(pQ + (size_t)blockIdx.x * 64 + c0) = Q4;
    }
}

// grid 64 (one block per channel), 256 threads. Reads [NBg][64] partials.
__global__ void finalize_kernel(const float* __restrict__ pS, const float* __restrict__ pQ,
                                int nbg, float invN,
                                const float* __restrict__ gamma,
                                const float* __restrict__ beta,
                                float* __restrict__ mr)
{
    __shared__ float rs_[256], rq_[256];
    const int o = blockIdx.x, t = threadIdx.x;
    float S = 0.f, Q = 0.f;
    for (int jj = t; jj < nbg; jj += 256) {
        S += pS[(size_t)jj * 64 + o];
        Q += pQ[(size_t)jj * 64 + o];
    }
    rs_[t] = S; rq_[t] = Q;
    __syncthreads();
#pragma unroll
    for (int s = 128; s > 0; s >>= 1) {
        if (t < s) { rs_[t] += rs_[t + s]; rq_[t] += rq_[t + s]; }
        __syncthreads();
    }
    if (t == 0) {
        const float mu  = rs_[0] * invN;
        const float var = rq_[0] * invN - mu * mu;
        const float rsg = rsqrtf(var + 1e-5f);
        const float sc  = gamma[o] * rsg;
        mr[o]      = sc;
        mr[64 + o] = fmaf(-sc, mu, beta[o]);
    }
}

// x2 = lrelu(aff2(Y2) + lrelu(aff1(Y1))): reads Y1,Y2 bf16 -> writes x2 bf16.
__global__ void norm_res_kernel(const unsigned short* __restrict__ y1,  // [M][64]
                                const unsigned short* __restrict__ y2,  // [M][64]
                                const float* __restrict__ mr1,
                                const float* __restrict__ mr2,
                                unsigned short* __restrict__ out,       // [M][64]
                                int N8)
{
    const int tid = blockIdx.x * blockDim.x + threadIdx.x;
    if (tid >= N8) return;
    const int c0 = (tid & 7) * 8;
    const ushort8_t a = *(const ushort8_t*)(y1 + (size_t)tid * 8);
    const ushort8_t b = *(const ushort8_t*)(y2 + (size_t)tid * 8);
    float r[8];
#pragma unroll
    for (int h = 0; h < 2; ++h) {
        const f32x4 s1 = *(const f32x4*)(mr1 + c0 + 4 * h);
        const f32x4 h1 = *(const f32x4*)(mr1 + 64 + c0 + 4 * h);
        const f32x4 s2 = *(const f32x4*)(mr2 + c0 + 4 * h);
        const f32x4 h2 = *(const f32x4*)(mr2 + 64 + c0 + 4 * h);
#pragma unroll
        for (int i = 0; i < 4; ++i) {
            float x1 = fmaf(bf2f(a[4 * h + i]), s1[i], h1[i]);
            x1 = fmaxf(x1, 0.2f * x1);
            float v = fmaf(bf2f(b[4 * h + i]), s2[i], h2[i]) + x1;
            r[4 * h + i] = fmaxf(v, 0.2f * v);
        }
    }
    unsigned fw[4];
#pragma unroll
    for (int i = 0; i < 4; ++i) fw[i] = pk2(r[2 * i], r[2 * i + 1]);
    *(uint4*)(out + (size_t)tid * 8) = make_uint4(fw[0], fw[1], fw[2], fw[3]);
}

// Final BN+res+lrelu fused with transpose [B*F][64] -> [B][64][F] fp32 (d_out).
__global__ void norm_transpose_kernel(const unsigned short* __restrict__ y,   // bf16
                                      const unsigned short* __restrict__ res, // bf16
                                      const float* __restrict__ mr,
                                      float* __restrict__ out, int F)
{
    __shared__ float tile[64 * 65];
    const int b = blockIdx.y, f0 = blockIdx.x * 64, t = threadIdx.x;
    const int j = t >> 2, s = t & 3;
    const int f = f0 + j;
    if (f < F) {
        const size_t row = ((size_t)b * F + f) * 64;
#pragma unroll
        for (int i = 0; i < 2; ++i) {
            const int c0 = s * 16 + i * 8;
            const ushort8_t yv = *(const ushort8_t*)(y + row + c0);
            const ushort8_t rv = *(const ushort8_t*)(res + row + c0);
#pragma unroll
            for (int h = 0; h < 2; ++h) {
                const f32x4 sc = *(const f32x4*)(mr + c0 + 4 * h);
                const f32x4 sh = *(const f32x4*)(mr + 64 + c0 + 4 * h);
#pragma unroll
                for (int q = 0; q < 4; ++q) {
                    float vv = fmaf(bf2f(yv[4 * h + q]), sc[q], sh[q]) + bf2f(rv[4 * h + q]);
                    vv = fmaxf(vv, 0.2f * vv);
                    tile[(c0 + 4 * h + q) * 65 + j] = vv;
                }
            }
        }
    }
    __syncthreads();
    const int o = t >> 2;
    float* ob = out + ((size_t)b * 64 + o) * F + f0;
#pragma unroll
    for (int i = 0; i < 4; ++i) {
        const int fs = (i * 4 + s) * 4;
        if (f0 + fs < F) {
            f32x4 v;
#pragma unroll
            for (int q = 0; q < 4; ++q) v[q] = tile[o * 65 + fs + q];
            *(f32x4*)(ob + fs) = v;
        }
    }
}

extern "C" void kernel_launch(void* const* d_in, const int* in_sizes, int n_in,
                              void* d_out, int out_size, void* d_ws, size_t ws_size,
                              hipStream_t stream)
{
    const float* fe  = (const float*)d_in[0];
    const int*   gm  = (const int*)d_in[1];
    const float* w1  = (const float*)d_in[2];
    const float* b1  = (const float*)d_in[3];
    const float* w2a = (const float*)d_in[4];
    const float* b2a = (const float*)d_in[5];
    const float* w2b = (const float*)d_in[6];
    const float* b2b = (const float*)d_in[7];
    const float* g0  = (const float*)d_in[8];
    const float* be0 = (const float*)d_in[9];
    const float* g1  = (const float*)d_in[10];
    const float* be1 = (const float*)d_in[11];
    const float* g2  = (const float*)d_in[12];
    const float* be2 = (const float*)d_in[13];

    const int B = 4, O = 64;
    const int F = in_sizes[0] / (B * 32);
    const int M = B * F;
    const float invN = 1.0f / (float)M;
    const int nbx = (F + 63) / 64;
    const int nb  = nbx * B;

    // Workspace layout
    unsigned short* Y1 = (unsigned short*)d_ws;         // [M][64] bf16 (Y1, later Y3)
    unsigned short* Y2 = Y1 + (size_t)M * O;            // [M][64] bf16
    unsigned short* x2 = Y2 + (size_t)M * O;            // [M][64] bf16
    float* pS  = (float*)(x2 + (size_t)M * O);          // [<=2048][64]
    float* pQ  = pS + 2048 * 64;                        // [<=2048][64]
    float* mr1 = pQ + 2048 * 64;                        // [2][64]
    float* mr2 = mr1 + 128;
    float* mr3 = mr2 + 128;
    unsigned short* w1b  = (unsigned short*)(mr3 + 128);// [64][128]
    unsigned short* w2ab = w1b + 64 * 128;              // [64][256]
    unsigned short* w2bb = w2ab + 64 * 256;             // [64][256]
    unsigned short* fe_t = (unsigned short*)d_out;      // [B][F][32] bf16, dead after conv1

    dim3 blk(256);
    dim3 tgrid(nbx, B);
    const int N8 = M * 8;
    dim3 ngrid((N8 + 255) / 256);
    const int g1g = (nb < 1280) ? nb : 1280;            // conv1: 5 blocks/CU
    const int g2g = (nb < 1024) ? nb : 1024;            // conv2/3: 4 blocks/CU
    const int g3g = g2g;

    transpose_fe_kernel<<<tgrid, blk, 0, stream>>>(fe, fe_t, F,
                                                   w1, w2a, w2b, w1b, w2ab, w2bb);

    // Stage 1: conv1 -> Y1, block stats -> pS/pQ; finalize -> mr1
    conv_mfma_kernel<32, false><<<g1g, blk, 0, stream>>>(
        fe_t, gm, w1b, b1, nullptr, Y1, pS, pQ, nb, nbx, F);
    finalize_kernel<<<64, 256, 0, stream>>>(pS, pQ, g1g, invN, g0, be0, mr1);

    // Stage 2: conv2 gathers Y1 with inline norm1 -> Y2; finalize -> mr2
    conv_mfma_kernel<64, true><<<g2g, blk, 0, stream>>>(
        Y1, gm, w2ab, b2a, mr1, Y2, pS, pQ, nb, nbx, F);
    finalize_kernel<<<64, 256, 0, stream>>>(pS, pQ, g2g, invN, g1, be1, mr2);

    // x2 = lrelu(aff2(Y2) + lrelu(aff1(Y1)))
    norm_res_kernel<<<ngrid, blk, 0, stream>>>(Y1, Y2, mr1, mr2, x2, N8);

    // Stage 3: conv3 gathers x2 -> Y3 (reuses Y1 slot); finalize -> mr3
    conv_mfma_kernel<64, false><<<g3g, blk, 0, stream>>>(
        x2, gm, w2bb, b2b, nullptr, Y1, pS, pQ, nb, nbx, F);
    finalize_kernel<<<64, 256, 0, stream>>>(pS, pQ, g3g, invN, g2, be2, mr3);

    // out = lrelu(aff3(Y3) + x2), transposed to [B][64][F] fp32
    norm_transpose_kernel<<<tgrid, blk, 0, stream>>>(Y1, x2, mr3, (float*)d_out, F);
}

// Round 8
// 216.003 us; speedup vs baseline: 1.5663x; 1.1632x over previous
//
#include <hip/hip_runtime.h>
#include <hip/hip_bf16.h>
#include <math.h>

// DownConvFace: 3 stages of {mesh_conv -> BN(global stats) -> (+res) -> LeakyReLU(0.2)}
// B=4, F=50000, Cin=32/64/64, O=64, fp32 in/out.
//
// R14: R13's counters exposed the conv gather pathology: FETCH 107MB on a 25.6MB
// input = ZERO L2 reuse on the 3 random-neighbor rows (each XCD L2 sees all 4
// batches under tl+=NBg striding). Fix: EXACT R11 structure (best measured,
// 219.7us — LDS-tile stats pass, grids 1280/768/1024) + XCD-CHUNKED contiguous
// tile ranges in the persistent loop (R7-proven): bid -> xcd=bid&7, slot=bid>>3;
// nb split into 8 contiguous ranges (bijective); block steps by bpx=NBg/8 within
// its range. Each XCD's gathers then touch ~1/2 batch (6.4MB vs 4MB L2) instead
// of 25.6MB -> neighbor hit rate ~0 -> ~50-60%.
// R13's reg-stats + grid changes reverted (unattributed 31us regression).
// KEEP: persistent blocks, reg-staged gather pipeline, weights in VGPRs,
// kernel-boundary stats sync (R9: NO fence/atomics in persistent kernels),
// norm_res fusion, inline-norm gather in conv2, cvt_pk packing.

typedef __attribute__((ext_vector_type(8))) short short8;
typedef __attribute__((ext_vector_type(8))) unsigned short ushort8_t;
typedef __attribute__((ext_vector_type(4))) float f32x4;

__device__ inline unsigned short f2bf(float v) {
    union { float f; unsigned u; } x; x.f = v;
    unsigned r = x.u + 0x7fffu + ((x.u >> 16) & 1u);   // RNE
    return (unsigned short)(r >> 16);
}
__device__ inline float bf2f(unsigned short u) {
    union { unsigned u; float f; } x; x.u = ((unsigned)u) << 16; return x.f;
}
// packed RNE f32x2 -> bf16x2 (v_cvt_pk_bf16_f32); lo 16 bits = a, hi = b
__device__ inline unsigned pk2(float a, float b) {
    union { __hip_bfloat162 h; unsigned u; } c;
    c.h = __float22bfloat162_rn(make_float2(a, b));
    return c.u;
}

// fe [B][32][F] fp32 -> fe_t [B][F][32] bf16; first 160 blocks also cast weights.
// grid (ceil(F/64), B), block 256.
__global__ void transpose_fe_kernel(const float* __restrict__ fe,
                                    unsigned short* __restrict__ o, int F,
                                    const float* __restrict__ w1,
                                    const float* __restrict__ w2a,
                                    const float* __restrict__ w2b,
                                    unsigned short* __restrict__ w1b,
                                    unsigned short* __restrict__ w2ab,
                                    unsigned short* __restrict__ w2bb)
{
    __shared__ float tile[64 * 33];
    const int b = blockIdx.y;
    const int f0 = blockIdx.x * 64;
    const int t = threadIdx.x;

    {   // folded weight cast (w1: 8192 elems; w2a/w2b: 16384 each)
        const int bid = blockIdx.y * gridDim.x + blockIdx.x;
        if (bid < 32)       { const int i = bid * 256 + t;        w1b[i]  = f2bf(w1[i]);  }
        else if (bid < 96)  { const int i = (bid - 32) * 256 + t; w2ab[i] = f2bf(w2a[i]); }
        else if (bid < 160) { const int i = (bid - 96) * 256 + t; w2bb[i] = f2bf(w2b[i]); }
    }

    const int lane = t & 63;
    const int w = t >> 6;
    const int f = f0 + lane;
    if (f < F) {
#pragma unroll
        for (int i = 0; i < 8; ++i) {
            const int c = w * 8 + i;
            tile[lane * 33 + c] = fe[((size_t)b * 32 + c) * F + f];
        }
    }
    __syncthreads();
    const int j = t >> 2, s = t & 3;
    const int fj = f0 + j;
    if (fj < F) {
        unsigned fw[4];
#pragma unroll
        for (int i = 0; i < 4; ++i)
            fw[i] = pk2(tile[j * 33 + s * 8 + 2 * i], tile[j * 33 + s * 8 + 2 * i + 1]);
        *(uint4*)(o + ((size_t)b * F + fj) * 32 + s * 8) = make_uint4(fw[0], fw[1], fw[2], fw[3]);
    }
}

// Persistent fused mesh-conv GEMM + BN block-stats. Block 256 (4 waves), 64
// faces/tile. Wave wv owns channels [wv*16,wv*16+16); weights in VGPRs; LDS holds
// G (reused as fp32 tile). XCD-chunked contiguous tile ranges for L2 locality.
template <int CIN, bool NORM>
__launch_bounds__(256, (CIN == 32) ? 5 : (NORM ? 3 : 4))
__global__ void conv_mfma_kernel(const unsigned short* __restrict__ x,  // [B][F][CIN] bf16
                                 const int*   __restrict__ gidx,        // [B][F][3]
                                 const unsigned short* __restrict__ wb, // [64][K] bf16
                                 const float* __restrict__ bias,        // [64]
                                 const float* __restrict__ mrIn,        // [2][64] or null
                                 unsigned short* __restrict__ y,        // [B*F][64] bf16
                                 float* __restrict__ pS,                // [NBg][64]
                                 float* __restrict__ pQ,                // [NBg][64]
                                 int nb, int nbx, int F)
{
    constexpr int NSEG = CIN / 32;
    constexpr int K    = 4 * CIN;
    constexpr int RB   = 2 * K;                        // row bytes (pow2)
    constexpr int GB   = 64 * RB;                      // G bytes (16384 / 32768)
    constexpr int GREG = (GB > 17408) ? GB : 17408;    // G region also holds fp32 tile
    __shared__ __align__(16) unsigned char smem[GREG];
    float* tile = (float*)smem;                        // [64][68] fp32 (reuses G)

    const int NBg = gridDim.x;
    const int t = threadIdx.x;
    const int j = t >> 2, s = t & 3;                   // 4 threads per face/row
    const int lane = t & 63, wv = t >> 6;
    const int l15 = lane & 15, quad = lane >> 4;
    const int kb = quad * 8;

    unsigned char* grow = smem + j * RB;
    const int swz = (j & 7) << 4;

    // ---- XCD-chunked persistent mapping (bijective per-XCD contiguous ranges) ----
    const int bpx  = NBg >> 3;                         // blocks per XCD (NBg % 8 == 0)
    const int xcd  = blockIdx.x & 7, slot = blockIdx.x >> 3;
    const int qq   = nb >> 3, rr = nb & 7;
    const int lo   = (xcd < rr) ? xcd * (qq + 1) : rr * (qq + 1) + (xcd - rr) * qq;
    const int L    = qq + (xcd < rr ? 1 : 0);          // this XCD's tile count

    // ---- weights -> REGISTERS: row wv*16+l15, 16B col slice per (ksi,quad) ----
    short8 afr[K / 32];
    {
        const int ar = wv * 16 + l15;
#pragma unroll
        for (int ksi = 0; ksi < K / 32; ++ksi)
            afr[ksi] = *(const short8*)(wb + (size_t)ar * K + ksi * 32 + kb);
    }
    // ---- bias -> registers (channels wv*16+quad*4 .. +3) ----
    const f32x4 bias4 = *(const f32x4*)(bias + wv * 16 + quad * 4);

    // ---- NORM affine (per-channel, uniform over tiles) -> registers ----
    float scr[NSEG * 8], shr[NSEG * 8];
    if constexpr (NORM) {
#pragma unroll
        for (int i = 0; i < NSEG; ++i) {
            const int c0 = (i * 4 + s) * 8;
#pragma unroll
            for (int h = 0; h < 2; ++h) {
                const f32x4 a  = *(const f32x4*)(mrIn + c0 + 4 * h);
                const f32x4 sh = *(const f32x4*)(mrIn + 64 + c0 + 4 * h);
#pragma unroll
                for (int q = 0; q < 4; ++q) {
                    scr[i * 8 + 4 * h + q] = a[q];
                    shr[i * 8 + 4 * h + q] = sh[q];
                }
            }
        }
    }

    // ---- staging registers + running stats ----
    ushort8_t vc[NSEG], v0[NSEG], v1[NSEG], v2[NSEG];
    int gA0, gA1, gA2;                                 // gidx for next tile
    float S_acc = 0.f, Q_acc = 0.f;
    const int so = t & 63, sg = t >> 6;                // stats ownership (o, group)

    int u = slot;                                      // logical step within range

    if (u < L) {
        // prologue: gather tile lo+u (clamped rows; invalid faces masked later)
        {
            const int tl = lo + u;
            const int b0 = tl / nbx;
            const int f0 = (tl - b0 * nbx) * 64;
            const int fc = min(f0 + j, F - 1);
            const int* gp = gidx + ((size_t)b0 * F + fc) * 3;
            const int g0 = gp[0], g1 = gp[1], g2 = gp[2];
            const unsigned short* xb = x + (size_t)b0 * F * CIN;
            const unsigned short* pc = xb + (size_t)fc * CIN;
            const unsigned short* p0 = xb + (size_t)g0 * CIN;
            const unsigned short* p1 = xb + (size_t)g1 * CIN;
            const unsigned short* p2 = xb + (size_t)g2 * CIN;
#pragma unroll
            for (int i = 0; i < NSEG; ++i) {
                const int c0 = (i * 4 + s) * 8;
                vc[i] = *(const ushort8_t*)(pc + c0);
                v0[i] = *(const ushort8_t*)(p0 + c0);
                v1[i] = *(const ushort8_t*)(p1 + c0);
                v2[i] = *(const ushort8_t*)(p2 + c0);
            }
        }
        {   // prefetch gidx one step ahead
            const int tn = lo + min(u + bpx, L - 1);
            const int bn = tn / nbx;
            const int fn = min((tn - bn * nbx) * 64 + j, F - 1);
            const int* gp = gidx + ((size_t)bn * F + fn) * 3;
            gA0 = gp[0]; gA1 = gp[1]; gA2 = gp[2];
        }
    }

    for (; u < L; u += bpx) {
        const int tl = lo + u;
        const int b  = tl / nbx;
        const int f0 = (tl - b * nbx) * 64;

        // ---- feat(cur regs) -> LDS G (inline norm if NORM; cvt_pk packing) ----
#pragma unroll
        for (int i = 0; i < NSEG; ++i) {
            const int c0 = (i * 4 + s) * 8;
            unsigned fw[16];
#pragma unroll
            for (int q = 0; q < 8; ++q) {
                float ctr = bf2f(vc[i][q]);
                float a   = bf2f(v0[i][q]);
                float bb  = bf2f(v1[i][q]);
                float cc  = bf2f(v2[i][q]);
                if constexpr (NORM) {
                    const float sc_ = scr[i * 8 + q], sh_ = shr[i * 8 + q];
                    ctr = fmaf(ctr, sc_, sh_); ctr = fmaxf(ctr, 0.2f * ctr);
                    a   = fmaf(a,   sc_, sh_); a   = fmaxf(a,   0.2f * a);
                    bb  = fmaf(bb,  sc_, sh_); bb  = fmaxf(bb,  0.2f * bb);
                    cc  = fmaf(cc,  sc_, sh_); cc  = fmaxf(cc,  0.2f * cc);
                }
                const float su = a + bb + cc;
                const float dd = fabsf(a - bb) + fabsf(bb - cc) + fabsf(cc - a);
                const float mm = fmaxf(a, fmaxf(bb, cc));
                fw[2 * q]     = pk2(ctr, su);
                fw[2 * q + 1] = pk2(dd, mm);
            }
#pragma unroll
            for (int q4 = 0; q4 < 4; ++q4) {
                const int qb = 8 * c0 + 16 * q4;       // 16B chunk byte offset
                *(uint4*)(grow + (qb ^ swz)) =
                    make_uint4(fw[4 * q4], fw[4 * q4 + 1], fw[4 * q4 + 2], fw[4 * q4 + 3]);
            }
        }

        // ---- issue gathers for next tile; they fly over MFMA+epilogue ----
        {
            const int tn = lo + min(u + bpx, L - 1);
            const int bn = tn / nbx;
            const int fcn = min((tn - bn * nbx) * 64 + j, F - 1);
            const unsigned short* xb = x + (size_t)bn * F * CIN;
            const unsigned short* pc = xb + (size_t)fcn * CIN;
            const unsigned short* p0 = xb + (size_t)gA0 * CIN;
            const unsigned short* p1 = xb + (size_t)gA1 * CIN;
            const unsigned short* p2 = xb + (size_t)gA2 * CIN;
#pragma unroll
            for (int i = 0; i < NSEG; ++i) {
                const int c0 = (i * 4 + s) * 8;
                vc[i] = *(const ushort8_t*)(pc + c0);
                v0[i] = *(const ushort8_t*)(p0 + c0);
                v1[i] = *(const ushort8_t*)(p1 + c0);
                v2[i] = *(const ushort8_t*)(p2 + c0);
            }
            const int t2 = lo + min(u + 2 * bpx, L - 1);
            const int b2 = t2 / nbx;
            const int f2 = min((t2 - b2 * nbx) * 64 + j, F - 1);
            const int* gp = gidx + ((size_t)b2 * F + f2) * 3;
            gA0 = gp[0]; gA1 = gp[1]; gA2 = gp[2];
        }
        __syncthreads();                               // B1: G ready

        // ---- MFMA: weights from VGPRs, G rows (faces nt*16+l15) from LDS ----
        f32x4 acc[4];
#pragma unroll
        for (int nt = 0; nt < 4; ++nt) acc[nt] = (f32x4){0.f, 0.f, 0.f, 0.f};
#pragma unroll
        for (int ksi = 0; ksi < K / 32; ++ksi) {
            const int cb = 2 * (ksi * 32 + kb);
#pragma unroll
            for (int nt = 0; nt < 4; ++nt) {
                const int nr = nt * 16 + l15;
                const short8 bfr = *(const short8*)(smem + nr * RB + (cb ^ ((nr & 7) << 4)));
                acc[nt] = __builtin_amdgcn_mfma_f32_16x16x32_bf16(afr[ksi], bfr, acc[nt], 0, 0, 0);
            }
        }
        __syncthreads();                               // B2: G dead -> reuse as tile

        // ---- epilogue: acc -> LDS tile [face][68] (+bias from regs) ----
        {
            const int cb0 = wv * 16 + quad * 4;
#pragma unroll
            for (int nt = 0; nt < 4; ++nt) {
                const int face = nt * 16 + l15;
                *(f32x4*)(tile + face * 68 + cb0) = acc[nt] + bias4;
            }
        }
        __syncthreads();                               // B3: tile ready
        {   // pass A: accumulate per-(o,g) partials in registers across tiles
#pragma unroll
            for (int i = 0; i < 16; ++i) {
                const int f = sg + 4 * i;
                if (f0 + f < F) {
                    const float v = tile[f * 68 + so];
                    S_acc += v; Q_acc += v * v;
                }
            }
        }
        {   // pass B: coalesced bf16 Y store (cvt_pk packing)
            const int f = f0 + j;
            if (f < F) {
                unsigned fw[8];
#pragma unroll
                for (int ii = 0; ii < 8; ++ii)
                    fw[ii] = pk2(tile[j * 68 + s * 16 + 2 * ii],
                                 tile[j * 68 + s * 16 + 2 * ii + 1]);
                unsigned short* yp = y + ((size_t)b * F + f) * 64 + s * 16;
                *(uint4*)yp       = make_uint4(fw[0], fw[1], fw[2], fw[3]);
                *(uint4*)(yp + 8) = make_uint4(fw[4], fw[5], fw[6], fw[7]);
            }
        }
        __syncthreads();                               // B4: tile dead before next feat
    }

    // ---- tail: cross-wave LDS reduce, ONE [64] store per block. No fence. ----
    float* redS = (float*)smem;                        // [256] (tile region dead)
    float* redQ = redS + 256;                          // [256]
    redS[t] = S_acc; redQ[t] = Q_acc;
    __syncthreads();
    if (t < 64) {
        pS[(size_t)blockIdx.x * 64 + t] = redS[t] + redS[64 + t] + redS[128 + t] + redS[192 + t];
        pQ[(size_t)blockIdx.x * 64 + t] = redQ[t] + redQ[64 + t] + redQ[128 + t] + redQ[192 + t];
    }
}

// grid 64 (one block per channel), 256 threads. Reads [NBg][64] partials.
__global__ void finalize_kernel(const float* __restrict__ pS, const float* __restrict__ pQ,
                                int nbg, float invN,
                                const float* __restrict__ gamma,
                                const float* __restrict__ beta,
                                float* __restrict__ mr)
{
    __shared__ float rs_[256], rq_[256];
    const int o = blockIdx.x, t = threadIdx.x;
    float S = 0.f, Q = 0.f;
    for (int jj = t; jj < nbg; jj += 256) {
        S += pS[(size_t)jj * 64 + o];
        Q += pQ[(size_t)jj * 64 + o];
    }
    rs_[t] = S; rq_[t] = Q;
    __syncthreads();
#pragma unroll
    for (int s = 128; s > 0; s >>= 1) {
        if (t < s) { rs_[t] += rs_[t + s]; rq_[t] += rq_[t + s]; }
        __syncthreads();
    }
    if (t == 0) {
        const float mu  = rs_[0] * invN;
        const float var = rq_[0] * invN - mu * mu;
        const float rsg = rsqrtf(var + 1e-5f);
        const float sc  = gamma[o] * rsg;
        mr[o]      = sc;
        mr[64 + o] = fmaf(-sc, mu, beta[o]);
    }
}

// x2 = lrelu(aff2(Y2) + lrelu(aff1(Y1))): reads Y1,Y2 bf16 -> writes x2 bf16.
__global__ void norm_res_kernel(const unsigned short* __restrict__ y1,  // [M][64]
                                const unsigned short* __restrict__ y2,  // [M][64]
                                const float* __restrict__ mr1,
                                const float* __restrict__ mr2,
                                unsigned short* __restrict__ out,       // [M][64]
                                int N8)
{
    const int tid = blockIdx.x * blockDim.x + threadIdx.x;
    if (tid >= N8) return;
    const int c0 = (tid & 7) * 8;
    const ushort8_t a = *(const ushort8_t*)(y1 + (size_t)tid * 8);
    const ushort8_t b = *(const ushort8_t*)(y2 + (size_t)tid * 8);
    float r[8];
#pragma unroll
    for (int h = 0; h < 2; ++h) {
        const f32x4 s1 = *(const f32x4*)(mr1 + c0 + 4 * h);
        const f32x4 h1 = *(const f32x4*)(mr1 + 64 + c0 + 4 * h);
        const f32x4 s2 = *(const f32x4*)(mr2 + c0 + 4 * h);
        const f32x4 h2 = *(const f32x4*)(mr2 + 64 + c0 + 4 * h);
#pragma unroll
        for (int i = 0; i < 4; ++i) {
            float x1 = fmaf(bf2f(a[4 * h + i]), s1[i], h1[i]);
            x1 = fmaxf(x1, 0.2f * x1);
            float v = fmaf(bf2f(b[4 * h + i]), s2[i], h2[i]) + x1;
            r[4 * h + i] = fmaxf(v, 0.2f * v);
        }
    }
    unsigned fw[4];
#pragma unroll
    for (int i = 0; i < 4; ++i) fw[i] = pk2(r[2 * i], r[2 * i + 1]);
    *(uint4*)(out + (size_t)tid * 8) = make_uint4(fw[0], fw[1], fw[2], fw[3]);
}

// Final BN+res+lrelu fused with transpose [B*F][64] -> [B][64][F] fp32 (d_out).
__global__ void norm_transpose_kernel(const unsigned short* __restrict__ y,   // bf16
                                      const unsigned short* __restrict__ res, // bf16
                                      const float* __restrict__ mr,
                                      float* __restrict__ out, int F)
{
    __shared__ float tile[64 * 65];
    const int b = blockIdx.y, f0 = blockIdx.x * 64, t = threadIdx.x;
    const int j = t >> 2, s = t & 3;
    const int f = f0 + j;
    if (f < F) {
        const size_t row = ((size_t)b * F + f) * 64;
#pragma unroll
        for (int i = 0; i < 2; ++i) {
            const int c0 = s * 16 + i * 8;
            const ushort8_t yv = *(const ushort8_t*)(y + row + c0);
            const ushort8_t rv = *(const ushort8_t*)(res + row + c0);
#pragma unroll
            for (int h = 0; h < 2; ++h) {
                const f32x4 sc = *(const f32x4*)(mr + c0 + 4 * h);
                const f32x4 sh = *(const f32x4*)(mr + 64 + c0 + 4 * h);
#pragma unroll
                for (int q = 0; q < 4; ++q) {
                    float vv = fmaf(bf2f(yv[4 * h + q]), sc[q], sh[q]) + bf2f(rv[4 * h + q]);
                    vv = fmaxf(vv, 0.2f * vv);
                    tile[(c0 + 4 * h + q) * 65 + j] = vv;
                }
            }
        }
    }
    __syncthreads();
    const int o = t >> 2;
    float* ob = out + ((size_t)b * 64 + o) * F + f0;
#pragma unroll
    for (int i = 0; i < 4; ++i) {
        const int fs = (i * 4 + s) * 4;
        if (f0 + fs < F) {
            f32x4 v;
#pragma unroll
            for (int q = 0; q < 4; ++q) v[q] = tile[o * 65 + fs + q];
            *(f32x4*)(ob + fs) = v;
        }
    }
}

extern "C" void kernel_launch(void* const* d_in, const int* in_sizes, int n_in,
                              void* d_out, int out_size, void* d_ws, size_t ws_size,
                              hipStream_t stream)
{
    const float* fe  = (const float*)d_in[0];
    const int*   gm  = (const int*)d_in[1];
    const float* w1  = (const float*)d_in[2];
    const float* b1  = (const float*)d_in[3];
    const float* w2a = (const float*)d_in[4];
    const float* b2a = (const float*)d_in[5];
    const float* w2b = (const float*)d_in[6];
    const float* b2b = (const float*)d_in[7];
    const float* g0  = (const float*)d_in[8];
    const float* be0 = (const float*)d_in[9];
    const float* g1  = (const float*)d_in[10];
    const float* be1 = (const float*)d_in[11];
    const float* g2  = (const float*)d_in[12];
    const float* be2 = (const float*)d_in[13];

    const int B = 4, O = 64;
    const int F = in_sizes[0] / (B * 32);
    const int M = B * F;
    const float invN = 1.0f / (float)M;
    const int nbx = (F + 63) / 64;
    const int nb  = nbx * B;

    // Workspace layout
    unsigned short* Y1 = (unsigned short*)d_ws;         // [M][64] bf16 (Y1, later Y3)
    unsigned short* Y2 = Y1 + (size_t)M * O;            // [M][64] bf16
    unsigned short* x2 = Y2 + (size_t)M * O;            // [M][64] bf16
    float* pS  = (float*)(x2 + (size_t)M * O);          // [<=2048][64]
    float* pQ  = pS + 2048 * 64;                        // [<=2048][64]
    float* mr1 = pQ + 2048 * 64;                        // [2][64]
    float* mr2 = mr1 + 128;
    float* mr3 = mr2 + 128;
    unsigned short* w1b  = (unsigned short*)(mr3 + 128);// [64][128]
    unsigned short* w2ab = w1b + 64 * 128;              // [64][256]
    unsigned short* w2bb = w2ab + 64 * 256;             // [64][256]
    unsigned short* fe_t = (unsigned short*)d_out;      // [B][F][32] bf16, dead after conv1

    dim3 blk(256);
    dim3 tgrid(nbx, B);
    const int N8 = M * 8;
    dim3 ngrid((N8 + 255) / 256);
    const int g1g = (nb < 1280) ? (nb & ~7) : 1280;     // conv1: 5 blocks/CU
    const int g2g = (nb < 768)  ? (nb & ~7) : 768;      // conv2 (NORM): 3 blocks/CU
    const int g3g = (nb < 1024) ? (nb & ~7) : 1024;     // conv3: 4 blocks/CU

    transpose_fe_kernel<<<tgrid, blk, 0, stream>>>(fe, fe_t, F,
                                                   w1, w2a, w2b, w1b, w2ab, w2bb);

    // Stage 1: conv1 -> Y1, block stats -> pS/pQ; finalize -> mr1
    conv_mfma_kernel<32, false><<<g1g, blk, 0, stream>>>(
        fe_t, gm, w1b, b1, nullptr, Y1, pS, pQ, nb, nbx, F);
    finalize_kernel<<<64, 256, 0, stream>>>(pS, pQ, g1g, invN, g0, be0, mr1);

    // Stage 2: conv2 gathers Y1 with inline norm1 -> Y2; finalize -> mr2
    conv_mfma_kernel<64, true><<<g2g, blk, 0, stream>>>(
        Y1, gm, w2ab, b2a, mr1, Y2, pS, pQ, nb, nbx, F);
    finalize_kernel<<<64, 256, 0, stream>>>(pS, pQ, g2g, invN, g1, be1, mr2);

    // x2 = lrelu(aff2(Y2) + lrelu(aff1(Y1)))
    norm_res_kernel<<<ngrid, blk, 0, stream>>>(Y1, Y2, mr1, mr2, x2, N8);

    // Stage 3: conv3 gathers x2 -> Y3 (reuses Y1 slot); finalize -> mr3
    conv_mfma_kernel<64, false><<<g3g, blk, 0, stream>>>(
        x2, gm, w2bb, b2b, nullptr, Y1, pS, pQ, nb, nbx, F);
    finalize_kernel<<<64, 256, 0, stream>>>(pS, pQ, g3g, invN, g2, be2, mr3);

    // out = lrelu(aff3(Y3) + x2), transposed to [B][64][F] fp32
    norm_transpose_kernel<<<tgrid, blk, 0, stream>>>(Y1, x2, mr3, (float*)d_out, F);
}